// Round 13
// baseline (234.364 us; speedup 1.0000x reference)
//
#include <hip/hip_runtime.h>
#include <math.h>

// Problem constants (SHAPES fixed; EMB=HID=256, H=8, L=4, P=4)
#define NB    2
#define NQ    11253          // I == N == 92^2+46^2+23^2+12^2
#define NEMB  256
#define NHID  256
#define NH    8
#define NCP   32             // HID / H
#define MROWS (NB * NQ)      // 22506
#define NGRP  (NB * NQ * NH) // 180048

// Level geometry; starts: 0, 8464, 10580, 11109
__device__ __constant__ int LVL_H[4]     = {92, 46, 23, 12};
__device__ __constant__ int LVL_W[4]     = {92, 46, 23, 12};
__device__ __constant__ int LVL_START[4] = {0, 8464, 10580, 11109};

typedef float  f32x4   __attribute__((ext_vector_type(4)));
typedef __bf16 bf16x8  __attribute__((ext_vector_type(8)));
typedef __bf16 bf16x4v __attribute__((ext_vector_type(4)));
typedef short  s16x8   __attribute__((ext_vector_type(8)));  // MFMA operand view

// ---------------------------------------------------------------------------
// Weights: W [K=256][N] fp32 -> hi/lo bf16 planes, k-blocked col-major:
// plane[kb][col][32] with kb = k/32. Per-GEMM-iteration slice plane[kb] is a
// contiguous N*32 region -> fully coalesced staging reads.
// Same RNE values as the round-11/12 verified converter, new storage layout.
// ---------------------------------------------------------------------------
__global__ __launch_bounds__(256) void convert_w_T(
    const float* __restrict__ W_img, const float* __restrict__ W_q,
    const float* __restrict__ W_out,
    __bf16* __restrict__ WiTh, __bf16* __restrict__ WiTl,
    __bf16* __restrict__ WqTh, __bf16* __restrict__ WqTl,
    __bf16* __restrict__ WoTh, __bf16* __restrict__ WoTl)
{
    int idx = blockIdx.x * 256 + threadIdx.x;     // 0 .. 28671
    const float* W; __bf16 *Th, *Tl; int Nn, r;
    if (idx < 8192)       { W = W_img; Th = WiTh; Tl = WiTl; Nn = 256; r = idx; }
    else if (idx < 20480) { W = W_q;   Th = WqTh; Tl = WqTl; Nn = 384; r = idx - 8192; }
    else                  { W = W_out; Th = WoTh; Tl = WoTl; Nn = 256; r = idx - 20480; }
    const int n  = r % Nn;
    const int k0 = (r / Nn) * 8;
    bf16x8 h, l;
    #pragma unroll
    for (int j = 0; j < 8; ++j) {
        float v = W[(size_t)(k0 + j) * Nn + n];
        __bf16 hh = (__bf16)v;
        h[j] = hh; l[j] = (__bf16)(v - (float)hh);
    }
    const size_t dst = ((size_t)(k0 >> 5) * Nn + n) * 32 + (k0 & 31);
    *(bf16x8*)(Th + dst) = h;
    *(bf16x8*)(Tl + dst) = l;
}

// ---------------------------------------------------------------------------
// Full-N-column bf16-split MFMA GEMM: C[:, colOff..colOff+NCOLS) for a 64-row
// panel; A (K=256) is read EXACTLY ONCE per y-pass (the round-13 change: with
// BN=64/128 the A re-reads missed per-XCD L2 and streamed ~3-5x traffic from
// L3/HBM -- the measured ~50 us/GEMM invariance).
// 3-term split hh+hl+lh (rel err ~2^-16), bitwise-identical accumulation order
// to the verified round-12 kernel. 4 waves; wave w covers cols w*NCOLS/4..;
// frags 4(row) x NCOLS/64(col) of v_mfma_f32_16x16x32_bf16.
// Fragment maps (m89/m91, on-device verified r10-12): A row=lane&15,
// k=(lane>>4)*8+i; B col=lane&15 same k; D col=lane&15, row=(lane>>4)*4+reg.
// LDS k-stride 40 (80 B) -> 2-way bank aliasing only (free, m136).
// ---------------------------------------------------------------------------
#define LDK 40

template<int NCOLS, bool PREA>
__global__ __launch_bounds__(256) void gemm_fullN(
    const float* __restrict__ A32,
    const __bf16* __restrict__ AhG, const __bf16* __restrict__ AlG,
    const __bf16* __restrict__ BhP, const __bf16* __restrict__ BlP,
    const float* __restrict__ bias, float* __restrict__ C,
    int M, int NTOT)
{
    constexpr int NCW = NCOLS / 4;    // cols per wave (64 or 48)
    constexpr int NC  = NCW / 16;     // col frags per wave (4 or 3)
    __shared__ __bf16 Ah[64 * LDK];
    __shared__ __bf16 Al[64 * LDK];
    __shared__ __bf16 Bh[NCOLS * LDK];
    __shared__ __bf16 Bl[NCOLS * LDK];

    const int t      = threadIdx.x;
    const int brow   = blockIdx.x * 64;
    const int colOff = blockIdx.y * NCOLS;
    const int wave   = t >> 6;
    const int lane   = t & 63;
    const int l15    = lane & 15;
    const int l4     = lane >> 4;

    f32x4 acc[4][NC] = {};

    // A staging: thread t covers row t>>2, k-chunk (t&3)*8  (K fixed = 256)
    const int sr   = t >> 2;
    const int sk   = (t & 3) * 8;
    const int grow = brow + sr;

    for (int k0 = 0; k0 < 256; k0 += 32) {
        // ---- stage A (hi/lo)
        if constexpr (PREA) {
            s16x8 h = {}, l = {};
            if (grow < M) {
                h = *(const s16x8*)(AhG + (size_t)grow * 256 + k0 + sk);
                l = *(const s16x8*)(AlG + (size_t)grow * 256 + k0 + sk);
            }
            *(s16x8*)&Ah[sr * LDK + sk] = h;
            *(s16x8*)&Al[sr * LDK + sk] = l;
        } else {
            float va[8];
            if (grow < M) {
                const float* ap = A32 + (size_t)grow * 256 + k0 + sk;
                *(float4*)&va[0] = *(const float4*)(ap + 0);
                *(float4*)&va[4] = *(const float4*)(ap + 4);
            } else {
                #pragma unroll
                for (int i = 0; i < 8; ++i) va[i] = 0.f;
            }
            bf16x8 h, l;
            #pragma unroll
            for (int i = 0; i < 8; ++i) {
                __bf16 hh = (__bf16)va[i];
                h[i] = hh; l[i] = (__bf16)(va[i] - (float)hh);
            }
            *(bf16x8*)&Ah[sr * LDK + sk] = h;
            *(bf16x8*)&Al[sr * LDK + sk] = l;
        }
        // ---- stage B: contiguous coalesced read of plane[kb][colOff..][32]
        if (t < NCOLS) {
            const size_t pb = ((size_t)(k0 >> 5) * NTOT + colOff + t) * 32;
            const __bf16* hp = BhP + pb;
            const __bf16* lp = BlP + pb;
            s16x8 h0 = *(const s16x8*)(hp +  0), h1 = *(const s16x8*)(hp +  8);
            s16x8 h2 = *(const s16x8*)(hp + 16), h3 = *(const s16x8*)(hp + 24);
            s16x8 l0 = *(const s16x8*)(lp +  0), l1 = *(const s16x8*)(lp +  8);
            s16x8 l2 = *(const s16x8*)(lp + 16), l3 = *(const s16x8*)(lp + 24);
            __bf16* dh = &Bh[t * LDK];
            *(s16x8*)(dh +  0) = h0;  *(s16x8*)(dh +  8) = h1;
            *(s16x8*)(dh + 16) = h2;  *(s16x8*)(dh + 24) = h3;
            __bf16* dl = &Bl[t * LDK];
            *(s16x8*)(dl +  0) = l0;  *(s16x8*)(dl +  8) = l1;
            *(s16x8*)(dl + 16) = l2;  *(s16x8*)(dl + 24) = l3;
        }
        __syncthreads();

        // ---- fragments + MFMA
        s16x8 a_h[4], a_l[4];
        #pragma unroll
        for (int mi = 0; mi < 4; ++mi) {
            int off = (mi * 16 + l15) * LDK + l4 * 8;
            a_h[mi] = *(s16x8*)&Ah[off];
            a_l[mi] = *(s16x8*)&Al[off];
        }
        #pragma unroll
        for (int ni = 0; ni < NC; ++ni) {
            int off = (wave * NCW + ni * 16 + l15) * LDK + l4 * 8;
            s16x8 b_h = *(s16x8*)&Bh[off];
            s16x8 b_l = *(s16x8*)&Bl[off];
            #pragma unroll
            for (int mi = 0; mi < 4; ++mi) {
                acc[mi][ni] = __builtin_amdgcn_mfma_f32_16x16x32_bf16(a_h[mi], b_h, acc[mi][ni], 0, 0, 0);
                acc[mi][ni] = __builtin_amdgcn_mfma_f32_16x16x32_bf16(a_h[mi], b_l, acc[mi][ni], 0, 0, 0);
                acc[mi][ni] = __builtin_amdgcn_mfma_f32_16x16x32_bf16(a_l[mi], b_h, acc[mi][ni], 0, 0, 0);
            }
        }
        __syncthreads();
    }

    // ---- epilogue: D map col=lane&15, row=(lane>>4)*4+reg
    #pragma unroll
    for (int ni = 0; ni < NC; ++ni) {
        const int gcol = colOff + wave * NCW + ni * 16 + l15;
        const float bv = bias[gcol];
        #pragma unroll
        for (int mi = 0; mi < 4; ++mi) {
            #pragma unroll
            for (int j = 0; j < 4; ++j) {
                int row = brow + mi * 16 + l4 * 4 + j;
                if (row < M) C[(size_t)row * NTOT + gcol] = acc[mi][ni][j] + bv;
            }
        }
    }
}

// ---------------------------------------------------------------------------
// Fused MSDA (byte-identical to round 10/11/12 verified version).
// 8 lanes per (b,n,h), lane = 4 channels (float4 gathers); hi/lo bf16 output.
// ---------------------------------------------------------------------------
__global__ __launch_bounds__(256) void msda_kernel(
    const float* __restrict__ img_p, const float* __restrict__ qp,
    const float* __restrict__ refp,
    __bf16* __restrict__ outH, __bf16* __restrict__ outL)
{
    __shared__ int smem[16][32][8];   // 16 KB
    const int t  = threadIdx.x;
    const int t3 = t & 7;
    const int g  = t >> 3;                 // group slot in block (0..31)
    int gid = blockIdx.x * 32 + g;         // (b*NQ+n)*NH + h
    const bool valid = gid < NGRP;
    if (!valid) gid = NGRP - 1;            // clamp: keep all lanes live for barrier
    const int h  = gid & 7;
    const int bn = gid >> 3;
    const int b  = (bn >= NQ) ? 1 : 0;

    const float* q  = qp + (size_t)bn * 384 + h * 48;
    const float rx = refp[bn * 2 + 0];
    const float ry = refp[bn * 2 + 1];

    const float ox0 = q[t3 * 3 + 0],        oy0 = q[t3 * 3 + 1],        sc0 = q[t3 * 3 + 2];
    const float ox1 = q[(t3 + 8) * 3 + 0],  oy1 = q[(t3 + 8) * 3 + 1],  sc1 = q[(t3 + 8) * 3 + 2];

    float mx = fmaxf(sc0, sc1);
    mx = fmaxf(mx, __shfl_xor(mx, 1, 8));
    mx = fmaxf(mx, __shfl_xor(mx, 2, 8));
    mx = fmaxf(mx, __shfl_xor(mx, 4, 8));
    const float e0 = __expf(sc0 - mx);
    const float e1 = __expf(sc1 - mx);
    float sum = e0 + e1;
    sum += __shfl_xor(sum, 1, 8);
    sum += __shfl_xor(sum, 2, 8);
    sum += __shfl_xor(sum, 4, 8);
    const float inv = 1.0f / sum;

    #pragma unroll
    for (int which = 0; which < 2; ++which) {
        const int   s  = which ? (t3 + 8) : t3;
        const float ox = which ? ox1 : ox0;
        const float oy = which ? oy1 : oy0;
        const float aw = (which ? e1 : e0) * inv;
        const int l  = s >> 2;
        const int hh = LVL_H[l], ww = LVL_W[l], st = LVL_START[l];
        float x = (rx + ox) * (float)(ww - 1);
        float y = (ry + oy) * (float)(hh - 1);
        x = fminf(fmaxf(x, 0.f), (float)(ww - 1));
        y = fminf(fmaxf(y, 0.f), (float)(hh - 1));
        const float x0f = floorf(x), y0f = floorf(y);
        const int   x0 = (int)x0f,  y0 = (int)y0f;
        const float wx = x - x0f,   wy = y - y0f;
        const int dxb = (x0 < ww - 1) ? (NH * NCP * 4) : 0;        // +1 col, bytes
        const int dyb = (y0 < hh - 1) ? (ww * NH * NCP * 4) : 0;   // +1 row, bytes
        const int o00 = (st + y0 * ww + x0) * (NH * NCP * 4);      // pixel byte offset
        const float u0 = aw * (1.f - wx), u1 = aw * wx;
        int4 pa = make_int4(o00, dxb, dyb, __float_as_int(u0 * (1.f - wy)));
        int4 pb = make_int4(__float_as_int(u1 * (1.f - wy)),
                            __float_as_int(u0 * wy),
                            __float_as_int(u1 * wy), 0);
        *(int4*)&smem[s][g][0] = pa;
        *(int4*)&smem[s][g][4] = pb;
    }
    __syncthreads();

    const char* base = (const char*)img_p
        + (((size_t)b * NQ * (NH * NCP) + h * NCP + t3 * 4) * 4);
    f32x4 acc = {0.f, 0.f, 0.f, 0.f};
    #pragma unroll
    for (int s = 0; s < 16; ++s) {
        const int4 pa = *(int4*)&smem[s][g][0];
        const int4 pb = *(int4*)&smem[s][g][4];
        const int o00 = pa.x;
        const int o01 = o00 + pa.y;
        const int o10 = o00 + pa.z;
        const int o11 = o10 + pa.y;
        const f32x4 v00 = *(const f32x4*)(base + o00);
        const f32x4 v01 = *(const f32x4*)(base + o01);
        const f32x4 v10 = *(const f32x4*)(base + o10);
        const f32x4 v11 = *(const f32x4*)(base + o11);
        acc += v00 * __int_as_float(pa.w);
        acc += v01 * __int_as_float(pb.x);
        acc += v10 * __int_as_float(pb.y);
        acc += v11 * __int_as_float(pb.z);
    }
    if (valid) {
        bf16x4v hv, lv;
        #pragma unroll
        for (int j = 0; j < 4; ++j) {
            __bf16 hh = (__bf16)acc[j];
            hv[j] = hh; lv[j] = (__bf16)(acc[j] - (float)hh);
        }
        const size_t o = (size_t)bn * NHID + h * NCP + t3 * 4;
        *(bf16x4v*)(outH + o) = hv;
        *(bf16x4v*)(outL + o) = lv;
    }
}

// ---------------------------------------------------------------------------
extern "C" void kernel_launch(void* const* d_in, const int* in_sizes, int n_in,
                              void* d_out, int out_size, void* d_ws, size_t ws_size,
                              hipStream_t stream) {
    const float* img     = (const float*)d_in[0];
    // d_in[1] = shapes (int32) -- hardcoded
    const float* queries = (const float*)d_in[2];
    const float* refp    = (const float*)d_in[3];
    const float* W_img   = (const float*)d_in[4];
    const float* b_img   = (const float*)d_in[5];
    const float* W_q     = (const float*)d_in[6];
    const float* b_q     = (const float*)d_in[7];
    const float* W_out   = (const float*)d_in[8];
    const float* b_out   = (const float*)d_in[9];
    float* out = (float*)d_out;

    // workspace (82.4 MB): img_p | qp | msdaH | msdaL | W planes (k-blocked)
    const size_t NA = (size_t)MROWS * 256;
    float*  img_p = (float*)d_ws;
    float*  qp    = img_p + NA;
    __bf16* msdaH = (__bf16*)(qp + (size_t)MROWS * 384);
    __bf16* msdaL = msdaH + NA;
    __bf16* WiTh  = msdaL + NA;
    __bf16* WiTl  = WiTh + 256 * 256;
    __bf16* WqTh  = WiTl + 256 * 256;
    __bf16* WqTl  = WqTh + 384 * 256;
    __bf16* WoTh  = WqTl + 384 * 256;
    __bf16* WoTl  = WoTh + 256 * 256;

    const int gRows = (MROWS + 63) / 64;   // 352

    // 0. weights -> k-blocked hi/lo bf16 planes
    convert_w_T<<<112, 256, 0, stream>>>(W_img, W_q, W_out,
                                         WiTh, WiTl, WqTh, WqTl, WoTh, WoTl);
    // 1. img_p = img @ W_img + b_img      (352 blocks, A read once)
    gemm_fullN<256, false><<<dim3(gRows, 1), 256, 0, stream>>>(
        img, nullptr, nullptr, WiTh, WiTl, b_img, img_p, MROWS, 256);
    // 2. qp = queries @ W_q + b_q         (352 x 2 col-passes of 192)
    gemm_fullN<192, false><<<dim3(gRows, 2), 256, 0, stream>>>(
        queries, nullptr, nullptr, WqTh, WqTl, b_q, qp, MROWS, 384);
    // 3. fused softmax + sampling + weighted sum -> hi/lo bf16
    msda_kernel<<<(NGRP + 31) / 32, 256, 0, stream>>>(img_p, qp, refp, msdaH, msdaL);
    // 4. out = msda_out @ W_out + b_out   (352 blocks, A read once)
    gemm_fullN<256, true><<<dim3(gRows, 1), 256, 0, stream>>>(
        nullptr, msdaH, msdaL, WoTh, WoTl, b_out, out, MROWS, 256);
}